// Round 7
// baseline (539.661 us; speedup 1.0000x reference)
//
#include <hip/hip_runtime.h>
#include <math.h>

// Problem constants
#define B_    256
#define N_    35
#define I_    64
#define H_    256
#define ROWS  8960            // B_*N_
#define ELEMS 2293760L        // ROWS*H_

typedef __bf16 bf16x8 __attribute__((ext_vector_type(8)));
typedef float f32x4 __attribute__((ext_vector_type(4)));

struct XPtrs { const float* p[12]; };
struct HPtrs { const float* p[7]; };
struct GB    { const __bf16* a0[12]; const __bf16* a1[12]; const float* hp[12]; };
struct MshA  { const __bf16* oa[4]; const __bf16* ob[4]; const __bf16* oc[4];
               const float* S[4]; __bf16* com; float* accs; };

#define GLOAD_LDS16(g, l) __builtin_amdgcn_global_load_lds( \
    (const __attribute__((address_space(1))) unsigned int*)(g), \
    (__attribute__((address_space(3))) unsigned int*)(l), 16, 0, 0)

#define SCHED0() __builtin_amdgcn_sched_barrier(0)
#define SBAR()   __builtin_amdgcn_s_barrier()

// ---------------- merged pre-work:
//   blk 0..23    compose adjacencies
//   blk 24..27   L1 norms
//   blk 28       zero accs
//   blk 29..1564 wc (GCN basis weights)
//   blk 1565..2236 wt (GRU weight transpose)
//   blk 2237..10076 hcast (hidden fp32 -> bf16, 8 elems/thread, 16B stores)
__global__ void pre_kernel(const float* __restrict__ As_, const float* __restrict__ Af_,
                           const float* __restrict__ At_, float* __restrict__ A12,
                           float* __restrict__ A12sq,
                           const float* __restrict__ S0, const float* __restrict__ S1,
                           const float* __restrict__ S2, const float* __restrict__ S3,
                           float* __restrict__ l1out, float* __restrict__ accs,
                           const float* __restrict__ V1, const float* __restrict__ c1,
                           const float* __restrict__ V2, const float* __restrict__ c2,
                           __bf16* __restrict__ WcT,
                           const float* __restrict__ Wr, const float* __restrict__ Wz,
                           const float* __restrict__ Wh, __bf16* __restrict__ WT,
                           HPtrs hp, __bf16* __restrict__ hbf) {
    __shared__ float shf[64 * 65];
    int blk = blockIdx.x;
    int tid = threadIdx.x;

    if (blk >= 2237) {                    // hcast: 7 x 1120 blocks, 8 elems/thread
        int t = blk - 2237;
        int gg = t / 1120;
        int bx = t - gg * 1120;
        long idx = ((long)bx * 256 + tid) * 8;
        const float4* s = (const float4*)(hp.p[gg] + idx);
        float4 v0 = s[0], v1 = s[1];
        bf16x8 o8;
        o8[0] = (__bf16)v0.x; o8[1] = (__bf16)v0.y; o8[2] = (__bf16)v0.z; o8[3] = (__bf16)v0.w;
        o8[4] = (__bf16)v1.x; o8[5] = (__bf16)v1.y; o8[6] = (__bf16)v1.z; o8[7] = (__bf16)v1.w;
        *(bf16x8*)(hbf + (long)gg * ELEMS + idx) = o8;
        return;
    }
    if (blk >= 1565) {                    // wt
        int t = blk - 1565;
        int z = t >> 5;
        int rem = t & 31;
        int bx = rem & 3, by = rem >> 2;
        int mat = z / 7, gg = z % 7;
        const float* srcs[3] = {Wr, Wz, Wh};
        const float* src = srcs[mat] + (long)gg * 512 * 256;
        __bf16* dst = WT + ((long)mat * 7 + gg) * 256 * 512;
        int n0 = bx * 64;
        int k0 = by * 64;
        float (*T)[65] = (float(*)[65])shf;
        int c = tid & 63, r0 = tid >> 6;
        for (int r = r0; r < 64; r += 4)
            T[r][c] = src[(long)(k0 + r) * 256 + n0 + c];
        __syncthreads();
        for (int n = r0; n < 64; n += 4)
            dst[(long)(n0 + n) * 512 + k0 + c] = (__bf16)T[c][n];
        return;
    }
    if (blk >= 29) {                      // wc
        int idx = (blk - 29) * 256 + tid;
        int k = idx & 127;
        int o = (idx >> 7) & 255;
        int r = idx >> 15;
        float acc = 0.f;
        if (k < 64) {
            for (int bb = 0; bb < 4; bb++) acc += c1[r*4+bb] * V1[((long)bb*64 + k)*256 + o];
        } else {
            int kk = k - 64;
            for (int bb = 0; bb < 4; bb++) acc += c2[r*4+bb] * V2[((long)bb*64 + kk)*256 + o];
        }
        WcT[idx] = (__bf16)acc;
        return;
    }
    if (blk >= 28) {
        if (tid < 8) accs[tid] = 0.f;
        return;
    }
    if (blk >= 24) {                      // L1
        const float* mats[4] = {S0, S1, S2, S3};
        const float* S = mats[blk - 24];
        float s = 0.f;
        for (int i = tid; i < N_ * N_; i += 256) s += fabsf(S[i]);
        for (int off = 32; off > 0; off >>= 1) s += __shfl_down(s, off);
        __shared__ float wr[4];
        if ((tid & 63) == 0) wr[tid >> 6] = s;
        __syncthreads();
        if (tid == 0) l1out[blk - 24] = wr[0] + wr[1] + wr[2] + wr[3];
        return;
    }
    int v = blk / 12, r = blk % 12;
    float (*M)[N_ * N_] = (float(*)[N_ * N_])shf;
    for (int i = tid; i < N_ * N_; i += 256) {
        float a = As_[i], f = Af_[i], t = At_[i];
        if (v) { a *= a; f *= f; t *= t; }
        M[0][i] = a; M[1][i] = f; M[2][i] = t;
    }
    __syncthreads();
    const int kind[12] = {0,0,0, 1,1,1,1,1,1, 2,2,2};
    const int ia[12]   = {0,1,2, 0,1,0,2,1,2, 0,0,2};
    const int ib[12]   = {0,1,2, 1,0,2,0,2,1, 1,2,0};
    const int ic[12]   = {0,0,0, 0,0,0,0,0,0, 2,1,1};
    const float* Ma = M[ia[r]];
    const float* Mb = M[ib[r]];
    const float* Mc = M[ic[r]];
    float* dst = (v ? A12sq : A12) + r * N_ * N_;
    for (int i = tid; i < N_ * N_; i += 256) {
        int m = i / N_, n = i % N_;
        float acc;
        if (kind[r] == 0) {
            acc = Ma[i];
        } else if (kind[r] == 1) {
            acc = 0.f;
            for (int p = 0; p < N_; p++) acc += Ma[m*N_+p] * Mb[p*N_+n];
        } else {
            acc = 0.f;
            for (int p = 0; p < N_; p++) {
                float t = 0.f;
                for (int q = 0; q < N_; q++) t += Mb[p*N_+q] * Mc[q*N_+n];
                acc += Ma[m*N_+p] * t;
            }
        }
        dst[i] = acc;
    }
}

// ---------------- xA fold ----------------
__global__ __launch_bounds__(256)
void xa_kernel(XPtrs xp, const float* __restrict__ A12, const float* __restrict__ A12sq,
               __bf16* __restrict__ xAc) {
    int r = blockIdx.x;
    int w = __builtin_amdgcn_readfirstlane(threadIdx.x >> 6);
    int v = w & 1, bl = w >> 1;
    int lane = threadIdx.x & 63;
    int b = blockIdx.y * 2 + bl;
    const float* x = xp.p[r] + (long)b * (N_ * I_);
    const float* As = (v ? A12sq : A12) + r * (N_ * N_);
    float xv[N_];
#pragma unroll
    for (int n = 0; n < N_; n++) xv[n] = x[n * I_ + lane];
    float acc[N_];
#pragma unroll
    for (int m = 0; m < N_; m++) acc[m] = 0.f;
#pragma unroll
    for (int n = 0; n < N_; n++) {
#pragma unroll
        for (int m = 0; m < N_; m++) acc[m] += As[m * N_ + n] * xv[n];
    }
    long obase = ((long)r * ROWS + (long)b * N_) * 128 + v * 64 + lane;
#pragma unroll
    for (int m = 0; m < N_; m++) xAc[obase + (long)m * 128] = (__bf16)acc[m];
}

// ---------------- bf16 MFMA GEMM (GCN), unchanged ----------------
template<int ACT>
__global__ __launch_bounds__(256)
void gemm_bf16(GB gb, int K0, int K, int lda0, int lda1,
               const __bf16* __restrict__ B0, const __bf16* __restrict__ B1,
               int N0, int ldb, long bstr,
               void* __restrict__ Cp, int ldc, long cstr,
               const __bf16* __restrict__ Zb, long zstr) {
    int bz = blockIdx.z;
    int n0 = blockIdx.x * 128;
    int m0 = blockIdx.y * 128;
    const __bf16* a0 = gb.a0[bz];
    const __bf16* a1 = gb.a1[bz];
    const __bf16* bbase = ((n0 < N0) ? B0 : B1) + bz * bstr;
    int nloc = (n0 < N0) ? n0 : (n0 - N0);
    __shared__ __bf16 As[2][8 * 512];
    __shared__ __bf16 Bs[2][8 * 512];
    int tid = threadIdx.x;
    int lane = tid & 63;
    int w = tid >> 6;
    int wm = (w & 1) * 64, wn = (w >> 1) * 64;
    int l15 = lane & 15, q = lane >> 4;
    int kq8 = q * 8;
    int ca = (w & 1) * 4;
    int cb = (w >> 1) * 4;
    f32x4 acc[4][4] = {};
    f32x4 accA[4][4];
    int ksplit = K >> 1;

    auto stage = [&](int buf, int kt2) {
        const __bf16* aseg; int kk; int lda;
        if (kt2 < K0) { aseg = a0; kk = kt2; lda = lda0; }
        else          { aseg = a1; kk = kt2 - K0; lda = lda1; }
        GLOAD_LDS16(aseg + (long)(m0 + w * 16 + l15) * lda + kk + kq8,      &As[buf][w * 512]);
        GLOAD_LDS16(aseg + (long)(m0 + 64 + w * 16 + l15) * lda + kk + kq8, &As[buf][(4 + w) * 512]);
        GLOAD_LDS16(bbase + (long)(nloc + w * 16 + l15) * ldb + kt2 + kq8,      &Bs[buf][w * 512]);
        GLOAD_LDS16(bbase + (long)(nloc + 64 + w * 16 + l15) * ldb + kt2 + kq8, &Bs[buf][(4 + w) * 512]);
    };

    stage(0, 0);
    int cur = 0;
    for (int kt = 0; kt < K; kt += 32) {
        __syncthreads();
        if (kt + 32 < K) stage(cur ^ 1, kt + 32);
        const __bf16* Ac = As[cur];
        const __bf16* Bc = Bs[cur];
        bf16x8 af[4], bfr[4];
#pragma unroll
        for (int mt = 0; mt < 4; mt++) af[mt]  = *(const bf16x8*)(Ac + (ca + mt) * 512 + q * 128 + l15 * 8);
#pragma unroll
        for (int nt = 0; nt < 4; nt++) bfr[nt] = *(const bf16x8*)(Bc + (cb + nt) * 512 + q * 128 + l15 * 8);
#pragma unroll
        for (int mt = 0; mt < 4; mt++)
#pragma unroll
            for (int nt = 0; nt < 4; nt++)
                acc[mt][nt] = __builtin_amdgcn_mfma_f32_16x16x32_bf16(af[mt], bfr[nt], acc[mt][nt], 0, 0, 0);
        if (ACT == 4 && (kt + 32) == ksplit) {
#pragma unroll
            for (int mt = 0; mt < 4; mt++)
#pragma unroll
                for (int nt = 0; nt < 4; nt++)
#pragma unroll
                    for (int r = 0; r < 4; r++) {
                        accA[mt][nt][r] = fmaxf(acc[mt][nt][r], 0.f);
                        acc[mt][nt][r] = 0.f;
                    }
        }
        cur ^= 1;
    }

#pragma unroll
    for (int mt = 0; mt < 4; mt++) {
#pragma unroll
        for (int nt = 0; nt < 4; nt++) {
#pragma unroll
            for (int r = 0; r < 4; r++) {
                long row = m0 + wm + mt*16 + q*4 + r;
                int col  = n0 + wn + nt*16 + l15;
                float vv = acc[mt][nt][r];
                ((__bf16*)Cp)[bz*cstr + row * ldc + col] = (__bf16)(accA[mt][nt][r] + fmaxf(vv, 0.f));
            }
        }
    }
}

// ---------------- fused GRU v7: ZERO-barrier K-loops ----------
// 64 rows x 512 cols, 8 waves. A = registers (2-deep E/O sets, per-wave global loads,
// L1-broadcast across waves). B = wave-private LDS chunks via global_load_lds, 2-deep.
// Phase-2 B reuses each wave's OWN phase-1 slots (no cross-wave LDS reuse) -> the only
// barrier in the kernel is the RH/ZB handoff. Per-wave counted vmcnt, SCHED0-fenced.
// LDS (bf16 elems): B 2x16384 @0, RH @32768, ZB @49152.  128 KB.
#define BBUF(b) (16384 * (b))
#define RHB 32768
#define ZBB 49152
__global__ __launch_bounds__(512, 2)
void gru_fused(GB gb, const __bf16* __restrict__ WT, float* __restrict__ outp) {
    __shared__ __bf16 sm[65536];     // 128 KB
    int g = blockIdx.y;
    int m0 = blockIdx.x * 64;
    int tid = threadIdx.x;
    int lane = tid & 63;
    int w = __builtin_amdgcn_readfirstlane(tid >> 6);   // 0..7
    int l15 = lane & 15, q = lane >> 4;
    int kq8 = q * 8;
    int qo = q * 128 + l15 * 8;
    int w4 = w * 4;
    const __bf16* __restrict__ ob  = gb.a0[g];
    const __bf16* __restrict__ hb  = gb.a1[g];
    const float*  __restrict__ hpg = gb.hp[g];
    const __bf16* wr_g = WT + (long)g * 131072;
    const __bf16* wz_g = WT + (long)(7 + g) * 131072;
    const __bf16* wh_g = WT + (long)(14 + g) * 131072;

    // A(t) -> registers: 4 frags (rows mt*16+l15, k (t&7)*32 + q*8). All waves same addrs.
    auto loadA1 = [&](bf16x8 (&d)[4], int t) {
        const __bf16* src = (t < 8) ? ob : hb;
#pragma unroll
        for (int mt = 0; mt < 4; mt++)
            d[mt] = *(const bf16x8*)(src + (long)(m0 + mt * 16 + l15) * 256 + (t & 7) * 32 + kq8);
    };
    // B(t) -> wave-private LDS chunks c = w*4..w*4+3 (gate cols 16c..16c+15).
    auto stageB1 = [&](int t) {
#pragma unroll
        for (int i = 0; i < 4; i++) {
            int c = w4 + i;
            const __bf16* bsrc = (c < 16) ? wr_g : wz_g;
            GLOAD_LDS16(bsrc + (long)((c & 15) * 16 + l15) * 512 + t * 32 + kq8,
                        &sm[BBUF(t & 1) + c * 512]);
        }
    };

    f32x4 acc[4][4] = {};
    bf16x8 aE[4], aO[4];
    // prologue: groups fenced so vmcnt retirement order is [A(0),B(0)],[A(1),B(1)]
    loadA1(aE, 0); stageB1(0); SCHED0();
    loadA1(aO, 1); stageB1(1); SCHED0();

    auto step1 = [&](bf16x8 (&aX)[4], int s) {
        bf16x8 bfr[4];
#pragma unroll
        for (int nt = 0; nt < 4; nt++)
            bfr[nt] = *(const bf16x8*)&sm[BBUF(s & 1) + (w4 + nt) * 512 + qo];
#pragma unroll
        for (int mt = 0; mt < 4; mt++)
#pragma unroll
            for (int nt = 0; nt < 4; nt++)
                acc[mt][nt] = __builtin_amdgcn_mfma_f32_16x16x32_bf16(aX[mt], bfr[nt], acc[mt][nt], 0, 0, 0);
    };

    // ---- phase 1: gates = [o|h] @ [Wr|Wz], 16 steps, NO barriers ----
#pragma unroll
    for (int su = 0; su < 16; su += 2) {
        asm volatile("s_waitcnt vmcnt(8)" ::: "memory");
        SCHED0();
        step1(aE, su);
        SCHED0();
        if (su + 2 < 16) { loadA1(aE, su + 2); stageB1(su + 2); }
        SCHED0();
        if (su + 1 < 15) { asm volatile("s_waitcnt vmcnt(8)" ::: "memory"); }
        else             { asm volatile("s_waitcnt vmcnt(0)" ::: "memory"); }
        SCHED0();
        step1(aO, su + 1);
        SCHED0();
        if (su + 3 < 16) { loadA1(aO, su + 3); stageB1(su + 3); }
        SCHED0();
    }

    // ---- phase-2 B: Wh logical chunks w*2..w*2+1, stored in THIS wave's slots w*4..w*4+1 ----
    auto stageB2 = [&](int t) {
#pragma unroll
        for (int i = 0; i < 2; i++)
            GLOAD_LDS16(wh_g + (long)((w * 2 + i) * 16 + l15) * 512 + t * 32 + kq8,
                        &sm[BBUF(t & 1) + (w4 + i) * 512]);
    };
    auto loadA2 = [&](bf16x8 (&d)[4], int t) {   // t = 8..15, o restage
#pragma unroll
        for (int mt = 0; mt < 4; mt++)
            d[mt] = *(const bf16x8*)(ob + (long)(m0 + mt * 16 + l15) * 256 + (t - 8) * 32 + kq8);
    };
    stageB2(0); SCHED0();
    stageB2(1); SCHED0();

    // ---- epilogue 1: waves 0-3 -> RH = sigmoid(r)*h (chunked); waves 4-7 -> ZB ----
    if (w < 4) {
#pragma unroll
        for (int mt = 0; mt < 4; mt++)
#pragma unroll
            for (int nt = 0; nt < 4; nt++)
#pragma unroll
                for (int j = 0; j < 4; j++) {
                    int row = mt * 16 + q * 4 + j;
                    int colg = w * 64 + nt * 16 + l15;
                    float rv = __builtin_amdgcn_rcpf(1.f + __expf(-acc[mt][nt][j]));
                    float hv = (float)hb[(long)(m0 + row) * 256 + colg];
                    int rhoff = RHB + ((w * 2 + (nt >> 1)) * 4 + mt) * 512
                              + ((nt * 2 + (l15 >> 3)) & 3) * 128 + (q * 4 + j) * 8 + (l15 & 7);
                    sm[rhoff] = (__bf16)(rv * hv);
                }
    } else {
        int wz4 = w - 4;
#pragma unroll
        for (int mt = 0; mt < 4; mt++)
#pragma unroll
            for (int nt = 0; nt < 4; nt++)
#pragma unroll
                for (int j = 0; j < 4; j++) {
                    int row = mt * 16 + q * 4 + j;
                    int colp = wz4 * 64 + nt * 16 + l15;
                    float zv = __builtin_amdgcn_rcpf(1.f + __expf(-acc[mt][nt][j]));
                    sm[ZBB + row * 256 + colp] = (__bf16)zv;
                }
    }
    asm volatile("s_waitcnt lgkmcnt(0)" ::: "memory");
    SCHED0();
    SBAR();                              // the ONLY barrier: RH/ZB visible
    SCHED0();

    // ---- phase 2: hh = [rh | o] @ Wh (64x256, K=512, 16 steps, NO barriers) ----
    f32x4 acc2[4][2] = {};
    auto step2rh = [&](int s) {          // s = 0..7: A from RH (LDS)
        bf16x8 a2[4], b2[2];
#pragma unroll
        for (int mt = 0; mt < 4; mt++)
            a2[mt] = *(const bf16x8*)&sm[RHB + (s * 4 + mt) * 512 + qo];
#pragma unroll
        for (int nt = 0; nt < 2; nt++)
            b2[nt] = *(const bf16x8*)&sm[BBUF(s & 1) + (w4 + nt) * 512 + qo];
#pragma unroll
        for (int mt = 0; mt < 4; mt++)
#pragma unroll
            for (int nt = 0; nt < 2; nt++)
                acc2[mt][nt] = __builtin_amdgcn_mfma_f32_16x16x32_bf16(a2[mt], b2[nt], acc2[mt][nt], 0, 0, 0);
    };
    auto step2rg = [&](bf16x8 (&aX)[4], int s) {  // s = 8..15: A from regs
        bf16x8 b2[2];
#pragma unroll
        for (int nt = 0; nt < 2; nt++)
            b2[nt] = *(const bf16x8*)&sm[BBUF(s & 1) + (w4 + nt) * 512 + qo];
#pragma unroll
        for (int mt = 0; mt < 4; mt++)
#pragma unroll
            for (int nt = 0; nt < 2; nt++)
                acc2[mt][nt] = __builtin_amdgcn_mfma_f32_16x16x32_bf16(aX[mt], b2[nt], acc2[mt][nt], 0, 0, 0);
    };

#pragma unroll
    for (int s = 0; s < 8; s++) {
        if (s < 7) { asm volatile("s_waitcnt vmcnt(2)" ::: "memory"); }
        else       { asm volatile("s_waitcnt vmcnt(6)" ::: "memory"); }
        SCHED0();
        step2rh(s);
        SCHED0();
        if (s == 6)      { stageB2(8); loadA2(aE, 8); }
        else if (s == 7) { stageB2(9); loadA2(aO, 9); }
        else             { stageB2(s + 2); }
        SCHED0();
    }
#pragma unroll
    for (int su = 8; su < 16; su += 2) {
        asm volatile("s_waitcnt vmcnt(6)" ::: "memory");
        SCHED0();
        step2rg(aE, su);
        SCHED0();
        if (su + 2 < 16) { stageB2(su + 2); loadA2(aE, su + 2); }
        SCHED0();
        if (su + 1 < 15) { asm volatile("s_waitcnt vmcnt(6)" ::: "memory"); }
        else             { asm volatile("s_waitcnt vmcnt(0)" ::: "memory"); }
        SCHED0();
        step2rg(aO, su + 1);
        SCHED0();
        if (su + 3 < 16) { stageB2(su + 3); loadA2(aO, su + 3); }
        SCHED0();
    }

    // ---- GRU epilogue: out = (1-z)*h + z*tanh(hh) ----
    float* og = outp + (long)g * ELEMS;
#pragma unroll
    for (int mt = 0; mt < 4; mt++)
#pragma unroll
        for (int nt = 0; nt < 2; nt++)
#pragma unroll
            for (int j = 0; j < 4; j++) {
                int row = mt * 16 + q * 4 + j;
                int col = w * 32 + nt * 16 + l15;
                float zz = (float)sm[ZBB + row * 256 + col];
                float e = __expf(2.f * acc2[mt][nt][j]);
                float th = 1.f - 2.f * __builtin_amdgcn_rcpf(e + 1.f);
                float hv = hpg[(long)(m0 + row) * 256 + col];
                og[(long)(m0 + row) * 256 + col] = (1.f - zz) * hv + zz * th;
            }
}

// ---------------- msh + sim + com ----------------
__global__ __launch_bounds__(256, 1)
void msh_kernel(MshA ma) {
    int z = blockIdx.z;
    bool tri = (z == 3);
    int b = blockIdx.x;
    int h0 = blockIdx.y * 64;
    int lane = threadIdx.x & 63;
    int w = __builtin_amdgcn_readfirstlane(threadIdx.x >> 6);
    long base = (long)b * N_ * H_ + h0 + lane;
    const __bf16* pa = ma.oa[z] + base;
    const __bf16* pb = ma.ob[z] + base;
    const __bf16* pc = ma.oc[z] + base;
    float av[N_], bv[N_], cv[N_];
#pragma unroll
    for (int n = 0; n < N_; n++) {
        av[n] = (float)pa[n * H_];
        bv[n] = (float)pb[n * H_];
    }
    if (tri) {
#pragma unroll
        for (int n = 0; n < N_; n++) cv[n] = (float)pc[n * H_];
    }
    const float* S = ma.S[z];
    __bf16* com = ma.com + (long)z * ELEMS + base;
    float lsum = 0.f;
    for (int mm = w; mm < N_; mm += 4) {
        float a = 0.f, bb = 0.f, cc = 0.f;
#pragma unroll
        for (int n = 0; n < N_; n++) {
            float s = S[n * N_ + mm];
            a += av[n] * s;
            bb += bv[n] * s;
            if (tri) cc += cv[n] * s;
        }
        if (tri) {
            com[(long)mm * H_] = (__bf16)((a + bb + cc) * (1.f/3.f));
            float d1 = a - bb, d2 = a - cc, d3 = bb - cc;
            lsum += d1*d1 + d2*d2 + d3*d3;
        } else {
            com[(long)mm * H_] = (__bf16)(0.5f * (a + bb));
            float d = a - bb;
            lsum += d * d;
        }
    }
    for (int off = 32; off > 0; off >>= 1) lsum += __shfl_down(lsum, off);
    __shared__ float wred[4];
    if (lane == 0) wred[w] = lsum;
    __syncthreads();
    if (threadIdx.x == 0) atomicAdd(ma.accs + z, wred[0] + wred[1] + wred[2] + wred[3]);
}

// ---------------- finalize sims ----------------
__global__ void fin_kernel(const float* __restrict__ accs, float* __restrict__ outp) {
    if (threadIdx.x == 0) {
        float inv = 1.f / 2293760.f;
        outp[0] = accs[0] * inv;
        outp[1] = accs[1] * inv;
        outp[2] = accs[2] * inv;
        outp[3] = accs[3] * inv;
    }
}

extern "C" void kernel_launch(void* const* d_in, const int* in_sizes, int n_in,
                              void* d_out, int out_size, void* d_ws, size_t ws_size,
                              hipStream_t stream) {
    const float* const* in = (const float* const*)d_in;
    float* out = (float*)d_out;
    char* ws = (char*)d_ws;

    size_t off = 0;
    auto alloc = [&](size_t bytes) { size_t o = off; off += (bytes + 255) & ~(size_t)255; return o; };
    float*  A12   = (float*)(ws + alloc(12*N_*N_*4));
    float*  A12sq = (float*)(ws + alloc(12*N_*N_*4));
    __bf16* WcT   = (__bf16*)(ws + alloc((size_t)12*256*128*2));
    __bf16* WT    = (__bf16*)(ws + alloc((size_t)21*256*512*2));
    float*  accs  = (float*)(ws + alloc(256));
    __bf16* gout  = (__bf16*)(ws + alloc((size_t)12*ELEMS*2));
    __bf16* com   = (__bf16*)(ws + alloc((size_t)4*ELEMS*2));
    __bf16* hbf   = (__bf16*)(ws + alloc((size_t)7*ELEMS*2));
    __bf16* xAc   = (__bf16*)(ws + alloc((size_t)12*ROWS*128*2));

    XPtrs xp;
    for (int i = 0; i < 12; i++) xp.p[i] = in[i];
    HPtrs hp;
    for (int i = 0; i < 7; i++) hp.p[i] = in[15 + i];

    pre_kernel<<<10077, 256, 0, stream>>>(in[12], in[13], in[14], A12, A12sq,
                                          in[27], in[26], in[28], in[29],
                                          out + 7L*ELEMS + 4, accs,
                                          in[22], in[23], in[24], in[25], WcT,
                                          in[30], in[31], in[32], WT,
                                          hp, hbf);
    xa_kernel<<<dim3(12, 128), 256, 0, stream>>>(xp, A12, A12sq, xAc);

    // GCN: gout[r] = relu(xA1@W1) + relu(xA2@W2)
    {
        GB gb{};
        for (int z = 0; z < 12; z++) { gb.a0[z] = xAc + (long)z*ROWS*128; gb.a1[z] = gb.a0[z]; }
        gemm_bf16<4><<<dim3(2, 70, 12), 256, 0, stream>>>(
            gb, 128, 128, 128, 128,
            WcT, WcT, 256, 128, 32768L,
            gout, 256, ELEMS, (const __bf16*)nullptr, 0L);
    }

    // msh + sim + com
    {
        MshA ma{};
        ma.oa[0] = gout + 3L*ELEMS; ma.ob[0] = gout + 4L*ELEMS; ma.oc[0] = ma.oa[0];
        ma.oa[1] = gout + 5L*ELEMS; ma.ob[1] = gout + 6L*ELEMS; ma.oc[1] = ma.oa[1];
        ma.oa[2] = gout + 7L*ELEMS; ma.ob[2] = gout + 8L*ELEMS; ma.oc[2] = ma.oa[2];
        ma.oa[3] = gout + 9L*ELEMS; ma.ob[3] = gout + 10L*ELEMS; ma.oc[3] = gout + 11L*ELEMS;
        ma.S[0] = in[26]; ma.S[1] = in[27]; ma.S[2] = in[28]; ma.S[3] = in[29];
        ma.com = com; ma.accs = accs;
        msh_kernel<<<dim3(256, 4, 4), 256, 0, stream>>>(ma);
    }

    fin_kernel<<<1, 64, 0, stream>>>(accs, out + 7L*ELEMS);

    // Fused GRU v7: zero-barrier K-loops, A in registers, wave-private B
    {
        GB gb{};
        for (int g = 0; g < 7; g++) {
            gb.a0[g] = (g < 3) ? gout + (long)g*ELEMS : com + (long)(g - 3)*ELEMS;
            gb.a1[g] = hbf + (long)g*ELEMS;
            gb.hp[g] = in[15 + g];
        }
        gru_fused<<<dim3(140, 7), 512, 0, stream>>>(gb, WT, out);
    }
}

// Round 8
// 490.761 us; speedup vs baseline: 1.0996x; 1.0996x over previous
//
#include <hip/hip_runtime.h>
#include <math.h>

// Problem constants
#define B_    256
#define N_    35
#define I_    64
#define H_    256
#define ROWS  8960            // B_*N_
#define ELEMS 2293760L        // ROWS*H_

typedef __bf16 bf16x8 __attribute__((ext_vector_type(8)));
typedef float f32x4 __attribute__((ext_vector_type(4)));

struct XPtrs { const float* p[12]; };
struct HPtrs { const float* p[7]; };
struct GB    { const __bf16* a0[12]; const __bf16* a1[12]; const float* hp[12]; };
struct MshA  { const __bf16* oa[4]; const __bf16* ob[4]; const __bf16* oc[4];
               const float* S[4]; __bf16* com; float* accs; };

#define GLOAD_LDS16(g, l) __builtin_amdgcn_global_load_lds( \
    (const __attribute__((address_space(1))) unsigned int*)(g), \
    (__attribute__((address_space(3))) unsigned int*)(l), 16, 0, 0)

#define SCHED0() __builtin_amdgcn_sched_barrier(0)
#define SBAR()   __builtin_amdgcn_s_barrier()

// ---------------- merged pre-work:
//   blk 0..23    compose adjacencies
//   blk 24..27   L1 norms
//   blk 28       zero accs
//   blk 29..1564 wc (GCN basis weights)
//   blk 1565..2236 wt (GRU weight transpose)
//   blk 2237..10076 hcast (hidden fp32 -> bf16, 8 elems/thread, 16B stores)
__global__ void pre_kernel(const float* __restrict__ As_, const float* __restrict__ Af_,
                           const float* __restrict__ At_, float* __restrict__ A12,
                           float* __restrict__ A12sq,
                           const float* __restrict__ S0, const float* __restrict__ S1,
                           const float* __restrict__ S2, const float* __restrict__ S3,
                           float* __restrict__ l1out, float* __restrict__ accs,
                           const float* __restrict__ V1, const float* __restrict__ c1,
                           const float* __restrict__ V2, const float* __restrict__ c2,
                           __bf16* __restrict__ WcT,
                           const float* __restrict__ Wr, const float* __restrict__ Wz,
                           const float* __restrict__ Wh, __bf16* __restrict__ WT,
                           HPtrs hp, __bf16* __restrict__ hbf) {
    __shared__ float shf[64 * 65];
    int blk = blockIdx.x;
    int tid = threadIdx.x;

    if (blk >= 2237) {                    // hcast: 7 x 1120 blocks, 8 elems/thread
        int t = blk - 2237;
        int gg = t / 1120;
        int bx = t - gg * 1120;
        long idx = ((long)bx * 256 + tid) * 8;
        const float4* s = (const float4*)(hp.p[gg] + idx);
        float4 v0 = s[0], v1 = s[1];
        bf16x8 o8;
        o8[0] = (__bf16)v0.x; o8[1] = (__bf16)v0.y; o8[2] = (__bf16)v0.z; o8[3] = (__bf16)v0.w;
        o8[4] = (__bf16)v1.x; o8[5] = (__bf16)v1.y; o8[6] = (__bf16)v1.z; o8[7] = (__bf16)v1.w;
        *(bf16x8*)(hbf + (long)gg * ELEMS + idx) = o8;
        return;
    }
    if (blk >= 1565) {                    // wt
        int t = blk - 1565;
        int z = t >> 5;
        int rem = t & 31;
        int bx = rem & 3, by = rem >> 2;
        int mat = z / 7, gg = z % 7;
        const float* srcs[3] = {Wr, Wz, Wh};
        const float* src = srcs[mat] + (long)gg * 512 * 256;
        __bf16* dst = WT + ((long)mat * 7 + gg) * 256 * 512;
        int n0 = bx * 64;
        int k0 = by * 64;
        float (*T)[65] = (float(*)[65])shf;
        int c = tid & 63, r0 = tid >> 6;
        for (int r = r0; r < 64; r += 4)
            T[r][c] = src[(long)(k0 + r) * 256 + n0 + c];
        __syncthreads();
        for (int n = r0; n < 64; n += 4)
            dst[(long)(n0 + n) * 512 + k0 + c] = (__bf16)T[c][n];
        return;
    }
    if (blk >= 29) {                      // wc
        int idx = (blk - 29) * 256 + tid;
        int k = idx & 127;
        int o = (idx >> 7) & 255;
        int r = idx >> 15;
        float acc = 0.f;
        if (k < 64) {
            for (int bb = 0; bb < 4; bb++) acc += c1[r*4+bb] * V1[((long)bb*64 + k)*256 + o];
        } else {
            int kk = k - 64;
            for (int bb = 0; bb < 4; bb++) acc += c2[r*4+bb] * V2[((long)bb*64 + kk)*256 + o];
        }
        WcT[idx] = (__bf16)acc;
        return;
    }
    if (blk >= 28) {
        if (tid < 8) accs[tid] = 0.f;
        return;
    }
    if (blk >= 24) {                      // L1
        const float* mats[4] = {S0, S1, S2, S3};
        const float* S = mats[blk - 24];
        float s = 0.f;
        for (int i = tid; i < N_ * N_; i += 256) s += fabsf(S[i]);
        for (int off = 32; off > 0; off >>= 1) s += __shfl_down(s, off);
        __shared__ float wr[4];
        if ((tid & 63) == 0) wr[tid >> 6] = s;
        __syncthreads();
        if (tid == 0) l1out[blk - 24] = wr[0] + wr[1] + wr[2] + wr[3];
        return;
    }
    int v = blk / 12, r = blk % 12;
    float (*M)[N_ * N_] = (float(*)[N_ * N_])shf;
    for (int i = tid; i < N_ * N_; i += 256) {
        float a = As_[i], f = Af_[i], t = At_[i];
        if (v) { a *= a; f *= f; t *= t; }
        M[0][i] = a; M[1][i] = f; M[2][i] = t;
    }
    __syncthreads();
    const int kind[12] = {0,0,0, 1,1,1,1,1,1, 2,2,2};
    const int ia[12]   = {0,1,2, 0,1,0,2,1,2, 0,0,2};
    const int ib[12]   = {0,1,2, 1,0,2,0,2,1, 1,2,0};
    const int ic[12]   = {0,0,0, 0,0,0,0,0,0, 2,1,1};
    const float* Ma = M[ia[r]];
    const float* Mb = M[ib[r]];
    const float* Mc = M[ic[r]];
    float* dst = (v ? A12sq : A12) + r * N_ * N_;
    for (int i = tid; i < N_ * N_; i += 256) {
        int m = i / N_, n = i % N_;
        float acc;
        if (kind[r] == 0) {
            acc = Ma[i];
        } else if (kind[r] == 1) {
            acc = 0.f;
            for (int p = 0; p < N_; p++) acc += Ma[m*N_+p] * Mb[p*N_+n];
        } else {
            acc = 0.f;
            for (int p = 0; p < N_; p++) {
                float t = 0.f;
                for (int q = 0; q < N_; q++) t += Mb[p*N_+q] * Mc[q*N_+n];
                acc += Ma[m*N_+p] * t;
            }
        }
        dst[i] = acc;
    }
}

// ---------------- xA fold ----------------
__global__ __launch_bounds__(256)
void xa_kernel(XPtrs xp, const float* __restrict__ A12, const float* __restrict__ A12sq,
               __bf16* __restrict__ xAc) {
    int r = blockIdx.x;
    int w = __builtin_amdgcn_readfirstlane(threadIdx.x >> 6);
    int v = w & 1, bl = w >> 1;
    int lane = threadIdx.x & 63;
    int b = blockIdx.y * 2 + bl;
    const float* x = xp.p[r] + (long)b * (N_ * I_);
    const float* As = (v ? A12sq : A12) + r * (N_ * N_);
    float xv[N_];
#pragma unroll
    for (int n = 0; n < N_; n++) xv[n] = x[n * I_ + lane];
    float acc[N_];
#pragma unroll
    for (int m = 0; m < N_; m++) acc[m] = 0.f;
#pragma unroll
    for (int n = 0; n < N_; n++) {
#pragma unroll
        for (int m = 0; m < N_; m++) acc[m] += As[m * N_ + n] * xv[n];
    }
    long obase = ((long)r * ROWS + (long)b * N_) * 128 + v * 64 + lane;
#pragma unroll
    for (int m = 0; m < N_; m++) xAc[obase + (long)m * 128] = (__bf16)acc[m];
}

// ---------------- bf16 MFMA GEMM (GCN), 128x128 tile, counted-vmcnt triple-buffer ----
// v2: raw s_barrier + per-wave vmcnt(4) (v6-proven sync) instead of __syncthreads drain.
// A/B triple-buffered (48 KB LDS -> 3 blocks/CU): stage into (s+2)%3 is safe for
// shared consumers (readers at steps s, s+1 touch s%3, (s+1)%3 only).
template<int ACT>
__global__ __launch_bounds__(256)
void gemm_bf16(GB gb, int K0, int K, int lda0, int lda1,
               const __bf16* __restrict__ B0, const __bf16* __restrict__ B1,
               int N0, int ldb, long bstr,
               void* __restrict__ Cp, int ldc, long cstr,
               const __bf16* __restrict__ Zb, long zstr) {
    int bz = blockIdx.z;
    int n0 = blockIdx.x * 128;
    int m0 = blockIdx.y * 128;
    const __bf16* a0 = gb.a0[bz];
    const __bf16* a1 = gb.a1[bz];
    const __bf16* bbase = ((n0 < N0) ? B0 : B1) + bz * bstr;
    int nloc = (n0 < N0) ? n0 : (n0 - N0);
    __shared__ __bf16 As[3][4096];
    __shared__ __bf16 Bs[3][4096];
    int tid = threadIdx.x;
    int lane = tid & 63;
    int w = tid >> 6;
    int wm = (w & 1) * 64, wn = (w >> 1) * 64;
    int l15 = lane & 15, q = lane >> 4;
    int kq8 = q * 8;
    int qo = q * 128 + l15 * 8;
    int ca = (w & 1) * 4;
    int cb = (w >> 1) * 4;
    f32x4 acc[4][4] = {};
    f32x4 accA[4][4];
    int nst = K >> 5;
    int ssplit = (K >> 6) - 1;           // split-relu after this step (ACT==4)

    auto stage = [&](int buf, int kt2) {
        const __bf16* aseg; int kk; int lda;
        if (kt2 < K0) { aseg = a0; kk = kt2; lda = lda0; }
        else          { aseg = a1; kk = kt2 - K0; lda = lda1; }
        GLOAD_LDS16(aseg + (long)(m0 + w * 16 + l15) * lda + kk + kq8,      &As[buf][w * 512]);
        GLOAD_LDS16(aseg + (long)(m0 + 64 + w * 16 + l15) * lda + kk + kq8, &As[buf][(4 + w) * 512]);
        GLOAD_LDS16(bbase + (long)(nloc + w * 16 + l15) * ldb + kt2 + kq8,      &Bs[buf][w * 512]);
        GLOAD_LDS16(bbase + (long)(nloc + 64 + w * 16 + l15) * ldb + kt2 + kq8, &Bs[buf][(4 + w) * 512]);
    };

    stage(0, 0); SCHED0();
    stage(1, 32); SCHED0();
    for (int s = 0; s < nst; s++) {
        if (s + 1 < nst) { asm volatile("s_waitcnt vmcnt(4)" ::: "memory"); }
        else             { asm volatile("s_waitcnt vmcnt(0)" ::: "memory"); }
        SCHED0();
        SBAR();
        SCHED0();
        if (s + 2 < nst) stage((s + 2) % 3, (s + 2) * 32);
        SCHED0();
        const __bf16* Ac = As[s % 3];
        const __bf16* Bc = Bs[s % 3];
        bf16x8 af[4], bfr[4];
#pragma unroll
        for (int mt = 0; mt < 4; mt++) af[mt]  = *(const bf16x8*)(Ac + (ca + mt) * 512 + qo);
#pragma unroll
        for (int nt = 0; nt < 4; nt++) bfr[nt] = *(const bf16x8*)(Bc + (cb + nt) * 512 + qo);
#pragma unroll
        for (int mt = 0; mt < 4; mt++)
#pragma unroll
            for (int nt = 0; nt < 4; nt++)
                acc[mt][nt] = __builtin_amdgcn_mfma_f32_16x16x32_bf16(af[mt], bfr[nt], acc[mt][nt], 0, 0, 0);
        SCHED0();
        if (ACT == 4 && s == ssplit) {
#pragma unroll
            for (int mt = 0; mt < 4; mt++)
#pragma unroll
                for (int nt = 0; nt < 4; nt++)
#pragma unroll
                    for (int r = 0; r < 4; r++) {
                        accA[mt][nt][r] = fmaxf(acc[mt][nt][r], 0.f);
                        acc[mt][nt][r] = 0.f;
                    }
        }
    }

#pragma unroll
    for (int mt = 0; mt < 4; mt++) {
#pragma unroll
        for (int nt = 0; nt < 4; nt++) {
#pragma unroll
            for (int r = 0; r < 4; r++) {
                long row = m0 + wm + mt*16 + q*4 + r;
                int col  = n0 + wn + nt*16 + l15;
                float vv = acc[mt][nt][r];
                ((__bf16*)Cp)[bz*cstr + row * ldc + col] = (__bf16)(accA[mt][nt][r] + fmaxf(vv, 0.f));
            }
        }
    }
}

// ---------------- fused GRU v6r: counted-vmcnt raw-barrier pipeline (round-6 verified) ----
// 64 rows x 512 cols, 8 waves. B staging wave-private (no barrier, counted vmcnt only);
// A (shared, 4KB/step) triple-buffered, staged 2 steps ahead; one raw s_barrier/step.
// r8 edit: final epilogue reads h from bf16 hbf (kills 64MB fp32 fetch); g-split launches.
// LDS (bf16 elems): A 3x2048 @0, B 2x16384 @6144, RH @38912, ZB @55296. 140 KB.
#define ABUF(b) (2048 * (b))
#define BBUF(b) (6144 + 16384 * (b))
#define RHB 38912
#define ZBB 55296
__global__ __launch_bounds__(512, 2)
void gru_fused(GB gb, const __bf16* __restrict__ WT, float* __restrict__ outp, int gbase) {
    __shared__ __bf16 sm[71680];     // 140 KB
    int g = gbase + blockIdx.y;
    int m0 = blockIdx.x * 64;
    int tid = threadIdx.x;
    int lane = tid & 63;
    int w = __builtin_amdgcn_readfirstlane(tid >> 6);   // 0..7
    bool wlt4 = (w < 4);
    int l15 = lane & 15, q = lane >> 4;
    int kq8 = q * 8;
    const __bf16* __restrict__ ob  = gb.a0[g];
    const __bf16* __restrict__ hb  = gb.a1[g];
    const __bf16* wr_g = WT + (long)g * 131072;
    const __bf16* wz_g = WT + (long)(7 + g) * 131072;
    const __bf16* wh_g = WT + (long)(14 + g) * 131072;

    auto stageA1 = [&](int t) {
        const __bf16* src = (t < 8) ? ob : hb;
        GLOAD_LDS16(src + (long)(m0 + w * 16 + l15) * 256 + (t & 7) * 32 + kq8,
                    &sm[ABUF(t % 3) + w * 512]);
    };
    auto stageB1 = [&](int t) {
#pragma unroll
        for (int i = 0; i < 4; i++) {
            int c = w * 4 + i;
            const __bf16* bsrc = (c < 16) ? wr_g : wz_g;
            int colloc = (c < 16) ? c * 16 : (c * 16 - 256);
            GLOAD_LDS16(bsrc + (long)(colloc + l15) * 512 + t * 32 + kq8,
                        &sm[BBUF(t & 1) + c * 512]);
        }
    };

    if (wlt4) stageA1(0);
    stageB1(0);
    if (wlt4) stageA1(1);
    stageB1(1);
    SCHED0();

    // ---- phase 1: gates = [o|h] @ [Wr|Wz], 16 K-steps ----
    f32x4 acc[4][4] = {};
#pragma unroll
    for (int s = 0; s < 16; s++) {
        if (s == 15)      { asm volatile("s_waitcnt vmcnt(0)" ::: "memory"); }
        else if (wlt4)    { asm volatile("s_waitcnt vmcnt(5)" ::: "memory"); }
        else              { asm volatile("s_waitcnt vmcnt(4)" ::: "memory"); }
        SCHED0();
        SBAR();
        SCHED0();
        if (wlt4 && s + 2 < 16) stageA1(s + 2);
        SCHED0();
        int as_ = ABUF(s % 3);
        int bs_ = BBUF(s & 1);
        bf16x8 af[4], bfr[4];
#pragma unroll
        for (int mt = 0; mt < 4; mt++)
            af[mt] = *(const bf16x8*)&sm[as_ + mt * 512 + q * 128 + l15 * 8];
#pragma unroll
        for (int nt = 0; nt < 4; nt++)
            bfr[nt] = *(const bf16x8*)&sm[bs_ + (w * 4 + nt) * 512 + q * 128 + l15 * 8];
#pragma unroll
        for (int mt = 0; mt < 4; mt++)
#pragma unroll
            for (int nt = 0; nt < 4; nt++)
                acc[mt][nt] = __builtin_amdgcn_mfma_f32_16x16x32_bf16(af[mt], bfr[nt], acc[mt][nt], 0, 0, 0);
        SCHED0();
        if (s + 2 < 16) stageB1(s + 2);
        SCHED0();
    }

    auto stageB2 = [&](int t) {
#pragma unroll
        for (int i = 0; i < 2; i++) {
            int c = w * 2 + i;
            GLOAD_LDS16(wh_g + (long)(c * 16 + l15) * 512 + t * 32 + kq8,
                        &sm[BBUF(t & 1) + c * 512]);
        }
    };
    auto stageA2 = [&](int t) {
        GLOAD_LDS16(ob + (long)(m0 + w * 16 + l15) * 256 + (t - 8) * 32 + kq8,
                    &sm[ABUF(t % 3) + w * 512]);
    };
    stageB2(0);
    stageB2(1);
    SCHED0();

    // ---- epilogue 1: waves 0-3 -> RH = sigmoid(r)*h (chunked); waves 4-7 -> ZB ----
    if (wlt4) {
#pragma unroll
        for (int mt = 0; mt < 4; mt++)
#pragma unroll
            for (int nt = 0; nt < 4; nt++)
#pragma unroll
                for (int j = 0; j < 4; j++) {
                    int row = mt * 16 + q * 4 + j;
                    int colg = w * 64 + nt * 16 + l15;
                    float rv = __builtin_amdgcn_rcpf(1.f + __expf(-acc[mt][nt][j]));
                    float hv = (float)hb[(long)(m0 + row) * 256 + colg];
                    int rhoff = RHB + ((w * 2 + (nt >> 1)) * 4 + mt) * 512
                              + ((nt * 2 + (l15 >> 3)) & 3) * 128 + (q * 4 + j) * 8 + (l15 & 7);
                    sm[rhoff] = (__bf16)(rv * hv);
                }
    } else {
        int w4 = w - 4;
#pragma unroll
        for (int mt = 0; mt < 4; mt++)
#pragma unroll
            for (int nt = 0; nt < 4; nt++)
#pragma unroll
                for (int j = 0; j < 4; j++) {
                    int row = mt * 16 + q * 4 + j;
                    int colp = w4 * 64 + nt * 16 + l15;
                    float zv = __builtin_amdgcn_rcpf(1.f + __expf(-acc[mt][nt][j]));
                    sm[ZBB + row * 256 + colp] = (__bf16)zv;
                }
    }
    asm volatile("s_waitcnt lgkmcnt(0)" ::: "memory");
    SCHED0();
    SBAR();                              // RH/ZB visible
    SCHED0();

    // ---- phase 2: hh = [rh | o] @ Wh (64x256, K=512, 16 steps) ----
    f32x4 acc2[4][2] = {};
#pragma unroll
    for (int s = 0; s < 16; s++) {
        if (s == 15)              { asm volatile("s_waitcnt vmcnt(0)" ::: "memory"); }
        else if (wlt4 && s >= 7)  { asm volatile("s_waitcnt vmcnt(3)" ::: "memory"); }
        else                      { asm volatile("s_waitcnt vmcnt(2)" ::: "memory"); }
        SCHED0();
        if (s >= 8) { SBAR(); SCHED0(); }
        if (wlt4 && s >= 6 && s + 2 < 16) stageA2(s + 2);
        SCHED0();
        int bs_ = BBUF(s & 1);
        bf16x8 a2[4], b2[2];
#pragma unroll
        for (int mt = 0; mt < 4; mt++)
            a2[mt] = (s < 8)
                ? *(const bf16x8*)&sm[RHB + (s * 4 + mt) * 512 + q * 128 + l15 * 8]
                : *(const bf16x8*)&sm[ABUF(s % 3) + mt * 512 + q * 128 + l15 * 8];
#pragma unroll
        for (int nt = 0; nt < 2; nt++)
            b2[nt] = *(const bf16x8*)&sm[bs_ + (w * 2 + nt) * 512 + q * 128 + l15 * 8];
#pragma unroll
        for (int mt = 0; mt < 4; mt++)
#pragma unroll
            for (int nt = 0; nt < 2; nt++)
                acc2[mt][nt] = __builtin_amdgcn_mfma_f32_16x16x32_bf16(a2[mt], b2[nt], acc2[mt][nt], 0, 0, 0);
        SCHED0();
        if (s + 2 < 16) stageB2(s + 2);
        SCHED0();
    }

    // ---- GRU epilogue: out = (1-z)*h + z*tanh(hh); h from bf16 hbf (L2-hot) ----
    float* og = outp + (long)g * ELEMS;
#pragma unroll
    for (int mt = 0; mt < 4; mt++)
#pragma unroll
        for (int nt = 0; nt < 2; nt++)
#pragma unroll
            for (int j = 0; j < 4; j++) {
                int row = mt * 16 + q * 4 + j;
                int col = w * 32 + nt * 16 + l15;
                float zz = (float)sm[ZBB + row * 256 + col];
                float e = __expf(2.f * acc2[mt][nt][j]);
                float th = 1.f - 2.f * __builtin_amdgcn_rcpf(e + 1.f);
                float hv = (float)hb[(long)(m0 + row) * 256 + col];
                og[(long)(m0 + row) * 256 + col] = (1.f - zz) * hv + zz * th;
            }
}

// ---------------- msh + sim + com ----------------
__global__ __launch_bounds__(256, 1)
void msh_kernel(MshA ma) {
    int z = blockIdx.z;
    bool tri = (z == 3);
    int b = blockIdx.x;
    int h0 = blockIdx.y * 64;
    int lane = threadIdx.x & 63;
    int w = __builtin_amdgcn_readfirstlane(threadIdx.x >> 6);
    long base = (long)b * N_ * H_ + h0 + lane;
    const __bf16* pa = ma.oa[z] + base;
    const __bf16* pb = ma.ob[z] + base;
    const __bf16* pc = ma.oc[z] + base;
    float av[N_], bv[N_], cv[N_];
#pragma unroll
    for (int n = 0; n < N_; n++) {
        av[n] = (float)pa[n * H_];
        bv[n] = (float)pb[n * H_];
    }
    if (tri) {
#pragma unroll
        for (int n = 0; n < N_; n++) cv[n] = (float)pc[n * H_];
    }
    const float* S = ma.S[z];
    __bf16* com = ma.com + (long)z * ELEMS + base;
    float lsum = 0.f;
    for (int mm = w; mm < N_; mm += 4) {
        float a = 0.f, bb = 0.f, cc = 0.f;
#pragma unroll
        for (int n = 0; n < N_; n++) {
            float s = S[n * N_ + mm];
            a += av[n] * s;
            bb += bv[n] * s;
            if (tri) cc += cv[n] * s;
        }
        if (tri) {
            com[(long)mm * H_] = (__bf16)((a + bb + cc) * (1.f/3.f));
            float d1 = a - bb, d2 = a - cc, d3 = bb - cc;
            lsum += d1*d1 + d2*d2 + d3*d3;
        } else {
            com[(long)mm * H_] = (__bf16)(0.5f * (a + bb));
            float d = a - bb;
            lsum += d * d;
        }
    }
    for (int off = 32; off > 0; off >>= 1) lsum += __shfl_down(lsum, off);
    __shared__ float wred[4];
    if (lane == 0) wred[w] = lsum;
    __syncthreads();
    if (threadIdx.x == 0) atomicAdd(ma.accs + z, wred[0] + wred[1] + wred[2] + wred[3]);
}

// ---------------- finalize sims ----------------
__global__ void fin_kernel(const float* __restrict__ accs, float* __restrict__ outp) {
    if (threadIdx.x == 0) {
        float inv = 1.f / 2293760.f;
        outp[0] = accs[0] * inv;
        outp[1] = accs[1] * inv;
        outp[2] = accs[2] * inv;
        outp[3] = accs[3] * inv;
    }
}

extern "C" void kernel_launch(void* const* d_in, const int* in_sizes, int n_in,
                              void* d_out, int out_size, void* d_ws, size_t ws_size,
                              hipStream_t stream) {
    const float* const* in = (const float* const*)d_in;
    float* out = (float*)d_out;
    char* ws = (char*)d_ws;

    size_t off = 0;
    auto alloc = [&](size_t bytes) { size_t o = off; off += (bytes + 255) & ~(size_t)255; return o; };
    float*  A12   = (float*)(ws + alloc(12*N_*N_*4));
    float*  A12sq = (float*)(ws + alloc(12*N_*N_*4));
    __bf16* WcT   = (__bf16*)(ws + alloc((size_t)12*256*128*2));
    __bf16* WT    = (__bf16*)(ws + alloc((size_t)21*256*512*2));
    float*  accs  = (float*)(ws + alloc(256));
    __bf16* gout  = (__bf16*)(ws + alloc((size_t)12*ELEMS*2));
    __bf16* com   = (__bf16*)(ws + alloc((size_t)4*ELEMS*2));
    __bf16* hbf   = (__bf16*)(ws + alloc((size_t)7*ELEMS*2));
    __bf16* xAc   = (__bf16*)(ws + alloc((size_t)12*ROWS*128*2));

    XPtrs xp;
    for (int i = 0; i < 12; i++) xp.p[i] = in[i];
    HPtrs hp;
    for (int i = 0; i < 7; i++) hp.p[i] = in[15 + i];

    pre_kernel<<<10077, 256, 0, stream>>>(in[12], in[13], in[14], A12, A12sq,
                                          in[27], in[26], in[28], in[29],
                                          out + 7L*ELEMS + 4, accs,
                                          in[22], in[23], in[24], in[25], WcT,
                                          in[30], in[31], in[32], WT,
                                          hp, hbf);
    xa_kernel<<<dim3(12, 128), 256, 0, stream>>>(xp, A12, A12sq, xAc);

    // GCN: gout[r] = relu(xA1@W1) + relu(xA2@W2)
    {
        GB gb{};
        for (int z = 0; z < 12; z++) { gb.a0[z] = xAc + (long)z*ROWS*128; gb.a1[z] = gb.a0[z]; }
        gemm_bf16<4><<<dim3(2, 70, 12), 256, 0, stream>>>(
            gb, 128, 128, 128, 128,
            WcT, WcT, 256, 128, 32768L,
            gout, 256, ELEMS, (const __bf16*)nullptr, 0L);
    }

    // msh + sim + com
    {
        MshA ma{};
        ma.oa[0] = gout + 3L*ELEMS; ma.ob[0] = gout + 4L*ELEMS; ma.oc[0] = ma.oa[0];
        ma.oa[1] = gout + 5L*ELEMS; ma.ob[1] = gout + 6L*ELEMS; ma.oc[1] = ma.oa[1];
        ma.oa[2] = gout + 7L*ELEMS; ma.ob[2] = gout + 8L*ELEMS; ma.oc[2] = ma.oa[2];
        ma.oa[3] = gout + 9L*ELEMS; ma.ob[3] = gout + 10L*ELEMS; ma.oc[3] = gout + 11L*ELEMS;
        ma.S[0] = in[26]; ma.S[1] = in[27]; ma.S[2] = in[28]; ma.S[3] = in[29];
        ma.com = com; ma.accs = accs;
        msh_kernel<<<dim3(256, 4, 4), 256, 0, stream>>>(ma);
    }

    fin_kernel<<<1, 64, 0, stream>>>(accs, out + 7L*ELEMS);

    // Fused GRU v6r: split launches (visibility threshold ~60 µs)
    {
        GB gb{};
        for (int g = 0; g < 7; g++) {
            gb.a0[g] = (g < 3) ? gout + (long)g*ELEMS : com + (long)(g - 3)*ELEMS;
            gb.a1[g] = hbf + (long)g*ELEMS;
            gb.hp[g] = in[15 + g];
        }
        gru_fused<<<dim3(140, 3), 512, 0, stream>>>(gb, WT, out, 0);
        gru_fused<<<dim3(140, 4), 512, 0, stream>>>(gb, WT, out, 3);
    }
}

// Round 9
// 454.897 us; speedup vs baseline: 1.1863x; 1.0788x over previous
//
#include <hip/hip_runtime.h>
#include <math.h>

// Problem constants
#define B_    256
#define N_    35
#define I_    64
#define H_    256
#define ROWS  8960            // B_*N_
#define ELEMS 2293760L        // ROWS*H_

typedef __bf16 bf16x8 __attribute__((ext_vector_type(8)));
typedef float f32x4 __attribute__((ext_vector_type(4)));

struct XPtrs { const float* p[12]; };
struct HPtrs { const float* p[7]; };
struct GB    { const __bf16* a0[12]; const __bf16* a1[12]; const float* hp[12]; };
struct MshA  { const __bf16* oa[4]; const __bf16* ob[4]; const __bf16* oc[4];
               const float* S[4]; __bf16* com; float* accs; };

#define GLOAD_LDS16(g, l) __builtin_amdgcn_global_load_lds( \
    (const __attribute__((address_space(1))) unsigned int*)(g), \
    (__attribute__((address_space(3))) unsigned int*)(l), 16, 0, 0)

#define SCHED0() __builtin_amdgcn_sched_barrier(0)
#define SBAR()   __builtin_amdgcn_s_barrier()

// ---------------- merged pre-work:
//   blk 0..23    compose adjacencies
//   blk 24..27   L1 norms
//   blk 28       zero accs
//   blk 29..1564 wc (GCN basis weights)
//   blk 1565..2236 wt (GRU weight transpose)
//   blk 2237..10076 hcast (hidden fp32 -> bf16, 8 elems/thread, 16B stores)
__global__ void pre_kernel(const float* __restrict__ As_, const float* __restrict__ Af_,
                           const float* __restrict__ At_, float* __restrict__ A12,
                           float* __restrict__ A12sq,
                           const float* __restrict__ S0, const float* __restrict__ S1,
                           const float* __restrict__ S2, const float* __restrict__ S3,
                           float* __restrict__ l1out, float* __restrict__ accs,
                           const float* __restrict__ V1, const float* __restrict__ c1,
                           const float* __restrict__ V2, const float* __restrict__ c2,
                           __bf16* __restrict__ WcT,
                           const float* __restrict__ Wr, const float* __restrict__ Wz,
                           const float* __restrict__ Wh, __bf16* __restrict__ WT,
                           HPtrs hp, __bf16* __restrict__ hbf) {
    __shared__ float shf[64 * 65];
    int blk = blockIdx.x;
    int tid = threadIdx.x;

    if (blk >= 2237) {                    // hcast: 7 x 1120 blocks, 8 elems/thread
        int t = blk - 2237;
        int gg = t / 1120;
        int bx = t - gg * 1120;
        long idx = ((long)bx * 256 + tid) * 8;
        const float4* s = (const float4*)(hp.p[gg] + idx);
        float4 v0 = s[0], v1 = s[1];
        bf16x8 o8;
        o8[0] = (__bf16)v0.x; o8[1] = (__bf16)v0.y; o8[2] = (__bf16)v0.z; o8[3] = (__bf16)v0.w;
        o8[4] = (__bf16)v1.x; o8[5] = (__bf16)v1.y; o8[6] = (__bf16)v1.z; o8[7] = (__bf16)v1.w;
        *(bf16x8*)(hbf + (long)gg * ELEMS + idx) = o8;
        return;
    }
    if (blk >= 1565) {                    // wt
        int t = blk - 1565;
        int z = t >> 5;
        int rem = t & 31;
        int bx = rem & 3, by = rem >> 2;
        int mat = z / 7, gg = z % 7;
        const float* srcs[3] = {Wr, Wz, Wh};
        const float* src = srcs[mat] + (long)gg * 512 * 256;
        __bf16* dst = WT + ((long)mat * 7 + gg) * 256 * 512;
        int n0 = bx * 64;
        int k0 = by * 64;
        float (*T)[65] = (float(*)[65])shf;
        int c = tid & 63, r0 = tid >> 6;
        for (int r = r0; r < 64; r += 4)
            T[r][c] = src[(long)(k0 + r) * 256 + n0 + c];
        __syncthreads();
        for (int n = r0; n < 64; n += 4)
            dst[(long)(n0 + n) * 512 + k0 + c] = (__bf16)T[c][n];
        return;
    }
    if (blk >= 29) {                      // wc
        int idx = (blk - 29) * 256 + tid;
        int k = idx & 127;
        int o = (idx >> 7) & 255;
        int r = idx >> 15;
        float acc = 0.f;
        if (k < 64) {
            for (int bb = 0; bb < 4; bb++) acc += c1[r*4+bb] * V1[((long)bb*64 + k)*256 + o];
        } else {
            int kk = k - 64;
            for (int bb = 0; bb < 4; bb++) acc += c2[r*4+bb] * V2[((long)bb*64 + kk)*256 + o];
        }
        WcT[idx] = (__bf16)acc;
        return;
    }
    if (blk >= 28) {
        if (tid < 8) accs[tid] = 0.f;
        return;
    }
    if (blk >= 24) {                      // L1
        const float* mats[4] = {S0, S1, S2, S3};
        const float* S = mats[blk - 24];
        float s = 0.f;
        for (int i = tid; i < N_ * N_; i += 256) s += fabsf(S[i]);
        for (int off = 32; off > 0; off >>= 1) s += __shfl_down(s, off);
        __shared__ float wr[4];
        if ((tid & 63) == 0) wr[tid >> 6] = s;
        __syncthreads();
        if (tid == 0) l1out[blk - 24] = wr[0] + wr[1] + wr[2] + wr[3];
        return;
    }
    int v = blk / 12, r = blk % 12;
    float (*M)[N_ * N_] = (float(*)[N_ * N_])shf;
    for (int i = tid; i < N_ * N_; i += 256) {
        float a = As_[i], f = Af_[i], t = At_[i];
        if (v) { a *= a; f *= f; t *= t; }
        M[0][i] = a; M[1][i] = f; M[2][i] = t;
    }
    __syncthreads();
    const int kind[12] = {0,0,0, 1,1,1,1,1,1, 2,2,2};
    const int ia[12]   = {0,1,2, 0,1,0,2,1,2, 0,0,2};
    const int ib[12]   = {0,1,2, 1,0,2,0,2,1, 1,2,0};
    const int ic[12]   = {0,0,0, 0,0,0,0,0,0, 2,1,1};
    const float* Ma = M[ia[r]];
    const float* Mb = M[ib[r]];
    const float* Mc = M[ic[r]];
    float* dst = (v ? A12sq : A12) + r * N_ * N_;
    for (int i = tid; i < N_ * N_; i += 256) {
        int m = i / N_, n = i % N_;
        float acc;
        if (kind[r] == 0) {
            acc = Ma[i];
        } else if (kind[r] == 1) {
            acc = 0.f;
            for (int p = 0; p < N_; p++) acc += Ma[m*N_+p] * Mb[p*N_+n];
        } else {
            acc = 0.f;
            for (int p = 0; p < N_; p++) {
                float t = 0.f;
                for (int q = 0; q < N_; q++) t += Mb[p*N_+q] * Mc[q*N_+n];
                acc += Ma[m*N_+p] * t;
            }
        }
        dst[i] = acc;
    }
}

// ---------------- xA fold ----------------
__global__ __launch_bounds__(256)
void xa_kernel(XPtrs xp, const float* __restrict__ A12, const float* __restrict__ A12sq,
               __bf16* __restrict__ xAc) {
    int r = blockIdx.x;
    int w = __builtin_amdgcn_readfirstlane(threadIdx.x >> 6);
    int v = w & 1, bl = w >> 1;
    int lane = threadIdx.x & 63;
    int b = blockIdx.y * 2 + bl;
    const float* x = xp.p[r] + (long)b * (N_ * I_);
    const float* As = (v ? A12sq : A12) + r * (N_ * N_);
    float xv[N_];
#pragma unroll
    for (int n = 0; n < N_; n++) xv[n] = x[n * I_ + lane];
    float acc[N_];
#pragma unroll
    for (int m = 0; m < N_; m++) acc[m] = 0.f;
#pragma unroll
    for (int n = 0; n < N_; n++) {
#pragma unroll
        for (int m = 0; m < N_; m++) acc[m] += As[m * N_ + n] * xv[n];
    }
    long obase = ((long)r * ROWS + (long)b * N_) * 128 + v * 64 + lane;
#pragma unroll
    for (int m = 0; m < N_; m++) xAc[obase + (long)m * 128] = (__bf16)acc[m];
}

// ---------------- bf16 MFMA GEMM (GCN), 128x128 tile, counted-vmcnt triple-buffer ----
template<int ACT>
__global__ __launch_bounds__(256)
void gemm_bf16(GB gb, int K0, int K, int lda0, int lda1,
               const __bf16* __restrict__ B0, const __bf16* __restrict__ B1,
               int N0, int ldb, long bstr,
               void* __restrict__ Cp, int ldc, long cstr,
               const __bf16* __restrict__ Zb, long zstr) {
    int bz = blockIdx.z;
    int n0 = blockIdx.x * 128;
    int m0 = blockIdx.y * 128;
    const __bf16* a0 = gb.a0[bz];
    const __bf16* a1 = gb.a1[bz];
    const __bf16* bbase = ((n0 < N0) ? B0 : B1) + bz * bstr;
    int nloc = (n0 < N0) ? n0 : (n0 - N0);
    __shared__ __bf16 As[3][4096];
    __shared__ __bf16 Bs[3][4096];
    int tid = threadIdx.x;
    int lane = tid & 63;
    int w = tid >> 6;
    int wm = (w & 1) * 64, wn = (w >> 1) * 64;
    int l15 = lane & 15, q = lane >> 4;
    int kq8 = q * 8;
    int qo = q * 128 + l15 * 8;
    int ca = (w & 1) * 4;
    int cb = (w >> 1) * 4;
    f32x4 acc[4][4] = {};
    f32x4 accA[4][4];
    int nst = K >> 5;
    int ssplit = (K >> 6) - 1;           // split-relu after this step (ACT==4)

    auto stage = [&](int buf, int kt2) {
        const __bf16* aseg; int kk; int lda;
        if (kt2 < K0) { aseg = a0; kk = kt2; lda = lda0; }
        else          { aseg = a1; kk = kt2 - K0; lda = lda1; }
        GLOAD_LDS16(aseg + (long)(m0 + w * 16 + l15) * lda + kk + kq8,      &As[buf][w * 512]);
        GLOAD_LDS16(aseg + (long)(m0 + 64 + w * 16 + l15) * lda + kk + kq8, &As[buf][(4 + w) * 512]);
        GLOAD_LDS16(bbase + (long)(nloc + w * 16 + l15) * ldb + kt2 + kq8,      &Bs[buf][w * 512]);
        GLOAD_LDS16(bbase + (long)(nloc + 64 + w * 16 + l15) * ldb + kt2 + kq8, &Bs[buf][(4 + w) * 512]);
    };

    stage(0, 0); SCHED0();
    stage(1, 32); SCHED0();
    for (int s = 0; s < nst; s++) {
        if (s + 1 < nst) { asm volatile("s_waitcnt vmcnt(4)" ::: "memory"); }
        else             { asm volatile("s_waitcnt vmcnt(0)" ::: "memory"); }
        SCHED0();
        SBAR();
        SCHED0();
        if (s + 2 < nst) stage((s + 2) % 3, (s + 2) * 32);
        SCHED0();
        const __bf16* Ac = As[s % 3];
        const __bf16* Bc = Bs[s % 3];
        bf16x8 af[4], bfr[4];
#pragma unroll
        for (int mt = 0; mt < 4; mt++) af[mt]  = *(const bf16x8*)(Ac + (ca + mt) * 512 + qo);
#pragma unroll
        for (int nt = 0; nt < 4; nt++) bfr[nt] = *(const bf16x8*)(Bc + (cb + nt) * 512 + qo);
#pragma unroll
        for (int mt = 0; mt < 4; mt++)
#pragma unroll
            for (int nt = 0; nt < 4; nt++)
                acc[mt][nt] = __builtin_amdgcn_mfma_f32_16x16x32_bf16(af[mt], bfr[nt], acc[mt][nt], 0, 0, 0);
        SCHED0();
        if (ACT == 4 && s == ssplit) {
#pragma unroll
            for (int mt = 0; mt < 4; mt++)
#pragma unroll
                for (int nt = 0; nt < 4; nt++)
#pragma unroll
                    for (int r = 0; r < 4; r++) {
                        accA[mt][nt][r] = fmaxf(acc[mt][nt][r], 0.f);
                        acc[mt][nt][r] = 0.f;
                    }
        }
    }

#pragma unroll
    for (int mt = 0; mt < 4; mt++) {
#pragma unroll
        for (int nt = 0; nt < 4; nt++) {
#pragma unroll
            for (int r = 0; r < 4; r++) {
                long row = m0 + wm + mt*16 + q*4 + r;
                int col  = n0 + wn + nt*16 + l15;
                float vv = acc[mt][nt][r];
                ((__bf16*)Cp)[bz*cstr + row * ldc + col] = (__bf16)(accA[mt][nt][r] + fmaxf(vv, 0.f));
            }
        }
    }
}

// ---------------- fused GRU v6s: single launch + bijective XCD-chunk swizzle ----
// Mechanism: default blockIdx round-robins across 8 XCDs -> each XCD touches all 7 g's
// B-panels (5.25 MB > 4 MB L2) -> B served from L3 at ~600-900cy, exceeding the 2-step
// vmcnt slack -> per-step convoy. Swizzle gives each XCD a contiguous ~122-block chunk
// (~one g) -> B L2-resident (768 KB), latency back inside the pipeline slack.
// LDS (bf16 elems): A 3x2048 @0, B 2x16384 @6144, RH @38912, ZB @55296. 140 KB.
#define ABUF(b) (2048 * (b))
#define BBUF(b) (6144 + 16384 * (b))
#define RHB 38912
#define ZBB 55296
__global__ __launch_bounds__(512, 2)
void gru_fused(GB gb, const __bf16* __restrict__ WT, float* __restrict__ outp) {
    __shared__ __bf16 sm[71680];     // 140 KB
    // bijective XCD-chunk swizzle (m204): nwg=980, q=122, r=4
    int nwg = gridDim.x;
    int qc = nwg >> 3, rc = nwg & 7;
    int xcd = blockIdx.x & 7, bidx = blockIdx.x >> 3;
    int sw = (xcd < rc) ? xcd * (qc + 1) + bidx : rc * (qc + 1) + (xcd - rc) * qc + bidx;
    int g = sw / 140;
    int m0 = (sw % 140) * 64;
    int tid = threadIdx.x;
    int lane = tid & 63;
    int w = __builtin_amdgcn_readfirstlane(tid >> 6);   // 0..7
    bool wlt4 = (w < 4);
    int l15 = lane & 15, q = lane >> 4;
    int kq8 = q * 8;
    const __bf16* __restrict__ ob  = gb.a0[g];
    const __bf16* __restrict__ hb  = gb.a1[g];
    const __bf16* wr_g = WT + (long)g * 131072;
    const __bf16* wz_g = WT + (long)(7 + g) * 131072;
    const __bf16* wh_g = WT + (long)(14 + g) * 131072;

    auto stageA1 = [&](int t) {
        const __bf16* src = (t < 8) ? ob : hb;
        GLOAD_LDS16(src + (long)(m0 + w * 16 + l15) * 256 + (t & 7) * 32 + kq8,
                    &sm[ABUF(t % 3) + w * 512]);
    };
    auto stageB1 = [&](int t) {
#pragma unroll
        for (int i = 0; i < 4; i++) {
            int c = w * 4 + i;
            const __bf16* bsrc = (c < 16) ? wr_g : wz_g;
            int colloc = (c < 16) ? c * 16 : (c * 16 - 256);
            GLOAD_LDS16(bsrc + (long)(colloc + l15) * 512 + t * 32 + kq8,
                        &sm[BBUF(t & 1) + c * 512]);
        }
    };

    if (wlt4) stageA1(0);
    stageB1(0);
    if (wlt4) stageA1(1);
    stageB1(1);
    SCHED0();

    // ---- phase 1: gates = [o|h] @ [Wr|Wz], 16 K-steps ----
    f32x4 acc[4][4] = {};
#pragma unroll
    for (int s = 0; s < 16; s++) {
        if (s == 15)      { asm volatile("s_waitcnt vmcnt(0)" ::: "memory"); }
        else if (wlt4)    { asm volatile("s_waitcnt vmcnt(5)" ::: "memory"); }
        else              { asm volatile("s_waitcnt vmcnt(4)" ::: "memory"); }
        SCHED0();
        SBAR();
        SCHED0();
        if (wlt4 && s + 2 < 16) stageA1(s + 2);
        SCHED0();
        int as_ = ABUF(s % 3);
        int bs_ = BBUF(s & 1);
        bf16x8 af[4], bfr[4];
#pragma unroll
        for (int mt = 0; mt < 4; mt++)
            af[mt] = *(const bf16x8*)&sm[as_ + mt * 512 + q * 128 + l15 * 8];
#pragma unroll
        for (int nt = 0; nt < 4; nt++)
            bfr[nt] = *(const bf16x8*)&sm[bs_ + (w * 4 + nt) * 512 + q * 128 + l15 * 8];
#pragma unroll
        for (int mt = 0; mt < 4; mt++)
#pragma unroll
            for (int nt = 0; nt < 4; nt++)
                acc[mt][nt] = __builtin_amdgcn_mfma_f32_16x16x32_bf16(af[mt], bfr[nt], acc[mt][nt], 0, 0, 0);
        SCHED0();
        if (s + 2 < 16) stageB1(s + 2);
        SCHED0();
    }

    auto stageB2 = [&](int t) {
#pragma unroll
        for (int i = 0; i < 2; i++) {
            int c = w * 2 + i;
            GLOAD_LDS16(wh_g + (long)(c * 16 + l15) * 512 + t * 32 + kq8,
                        &sm[BBUF(t & 1) + c * 512]);
        }
    };
    auto stageA2 = [&](int t) {
        GLOAD_LDS16(ob + (long)(m0 + w * 16 + l15) * 256 + (t - 8) * 32 + kq8,
                    &sm[ABUF(t % 3) + w * 512]);
    };
    stageB2(0);
    stageB2(1);
    SCHED0();

    // ---- epilogue 1: waves 0-3 -> RH = sigmoid(r)*h (chunked); waves 4-7 -> ZB ----
    if (wlt4) {
#pragma unroll
        for (int mt = 0; mt < 4; mt++)
#pragma unroll
            for (int nt = 0; nt < 4; nt++)
#pragma unroll
                for (int j = 0; j < 4; j++) {
                    int row = mt * 16 + q * 4 + j;
                    int colg = w * 64 + nt * 16 + l15;
                    float rv = __builtin_amdgcn_rcpf(1.f + __expf(-acc[mt][nt][j]));
                    float hv = (float)hb[(long)(m0 + row) * 256 + colg];
                    int rhoff = RHB + ((w * 2 + (nt >> 1)) * 4 + mt) * 512
                              + ((nt * 2 + (l15 >> 3)) & 3) * 128 + (q * 4 + j) * 8 + (l15 & 7);
                    sm[rhoff] = (__bf16)(rv * hv);
                }
    } else {
        int w4 = w - 4;
#pragma unroll
        for (int mt = 0; mt < 4; mt++)
#pragma unroll
            for (int nt = 0; nt < 4; nt++)
#pragma unroll
                for (int j = 0; j < 4; j++) {
                    int row = mt * 16 + q * 4 + j;
                    int colp = w4 * 64 + nt * 16 + l15;
                    float zv = __builtin_amdgcn_rcpf(1.f + __expf(-acc[mt][nt][j]));
                    sm[ZBB + row * 256 + colp] = (__bf16)zv;
                }
    }
    asm volatile("s_waitcnt lgkmcnt(0)" ::: "memory");
    SCHED0();
    SBAR();                              // RH/ZB visible
    SCHED0();

    // ---- phase 2: hh = [rh | o] @ Wh (64x256, K=512, 16 steps) ----
    f32x4 acc2[4][2] = {};
#pragma unroll
    for (int s = 0; s < 16; s++) {
        if (s == 15)              { asm volatile("s_waitcnt vmcnt(0)" ::: "memory"); }
        else if (wlt4 && s >= 7)  { asm volatile("s_waitcnt vmcnt(3)" ::: "memory"); }
        else                      { asm volatile("s_waitcnt vmcnt(2)" ::: "memory"); }
        SCHED0();
        if (s >= 8) { SBAR(); SCHED0(); }
        if (wlt4 && s >= 6 && s + 2 < 16) stageA2(s + 2);
        SCHED0();
        int bs_ = BBUF(s & 1);
        bf16x8 a2[4], b2[2];
#pragma unroll
        for (int mt = 0; mt < 4; mt++)
            a2[mt] = (s < 8)
                ? *(const bf16x8*)&sm[RHB + (s * 4 + mt) * 512 + q * 128 + l15 * 8]
                : *(const bf16x8*)&sm[ABUF(s % 3) + mt * 512 + q * 128 + l15 * 8];
#pragma unroll
        for (int nt = 0; nt < 2; nt++)
            b2[nt] = *(const bf16x8*)&sm[bs_ + (w * 2 + nt) * 512 + q * 128 + l15 * 8];
#pragma unroll
        for (int mt = 0; mt < 4; mt++)
#pragma unroll
            for (int nt = 0; nt < 2; nt++)
                acc2[mt][nt] = __builtin_amdgcn_mfma_f32_16x16x32_bf16(a2[mt], b2[nt], acc2[mt][nt], 0, 0, 0);
        SCHED0();
        if (s + 2 < 16) stageB2(s + 2);
        SCHED0();
    }

    // ---- GRU epilogue: out = (1-z)*h + z*tanh(hh); h from bf16 hbf (L2-hot) ----
    float* og = outp + (long)g * ELEMS;
#pragma unroll
    for (int mt = 0; mt < 4; mt++)
#pragma unroll
        for (int nt = 0; nt < 2; nt++)
#pragma unroll
            for (int j = 0; j < 4; j++) {
                int row = mt * 16 + q * 4 + j;
                int col = w * 32 + nt * 16 + l15;
                float zz = (float)sm[ZBB + row * 256 + col];
                float e = __expf(2.f * acc2[mt][nt][j]);
                float th = 1.f - 2.f * __builtin_amdgcn_rcpf(e + 1.f);
                float hv = (float)hb[(long)(m0 + row) * 256 + col];
                og[(long)(m0 + row) * 256 + col] = (1.f - zz) * hv + zz * th;
            }
}

// ---------------- msh + sim + com ----------------
__global__ __launch_bounds__(256, 1)
void msh_kernel(MshA ma) {
    int z = blockIdx.z;
    bool tri = (z == 3);
    int b = blockIdx.x;
    int h0 = blockIdx.y * 64;
    int lane = threadIdx.x & 63;
    int w = __builtin_amdgcn_readfirstlane(threadIdx.x >> 6);
    long base = (long)b * N_ * H_ + h0 + lane;
    const __bf16* pa = ma.oa[z] + base;
    const __bf16* pb = ma.ob[z] + base;
    const __bf16* pc = ma.oc[z] + base;
    float av[N_], bv[N_], cv[N_];
#pragma unroll
    for (int n = 0; n < N_; n++) {
        av[n] = (float)pa[n * H_];
        bv[n] = (float)pb[n * H_];
    }
    if (tri) {
#pragma unroll
        for (int n = 0; n < N_; n++) cv[n] = (float)pc[n * H_];
    }
    const float* S = ma.S[z];
    __bf16* com = ma.com + (long)z * ELEMS + base;
    float lsum = 0.f;
    for (int mm = w; mm < N_; mm += 4) {
        float a = 0.f, bb = 0.f, cc = 0.f;
#pragma unroll
        for (int n = 0; n < N_; n++) {
            float s = S[n * N_ + mm];
            a += av[n] * s;
            bb += bv[n] * s;
            if (tri) cc += cv[n] * s;
        }
        if (tri) {
            com[(long)mm * H_] = (__bf16)((a + bb + cc) * (1.f/3.f));
            float d1 = a - bb, d2 = a - cc, d3 = bb - cc;
            lsum += d1*d1 + d2*d2 + d3*d3;
        } else {
            com[(long)mm * H_] = (__bf16)(0.5f * (a + bb));
            float d = a - bb;
            lsum += d * d;
        }
    }
    for (int off = 32; off > 0; off >>= 1) lsum += __shfl_down(lsum, off);
    __shared__ float wred[4];
    if (lane == 0) wred[w] = lsum;
    __syncthreads();
    if (threadIdx.x == 0) atomicAdd(ma.accs + z, wred[0] + wred[1] + wred[2] + wred[3]);
}

// ---------------- finalize sims ----------------
__global__ void fin_kernel(const float* __restrict__ accs, float* __restrict__ outp) {
    if (threadIdx.x == 0) {
        float inv = 1.f / 2293760.f;
        outp[0] = accs[0] * inv;
        outp[1] = accs[1] * inv;
        outp[2] = accs[2] * inv;
        outp[3] = accs[3] * inv;
    }
}

extern "C" void kernel_launch(void* const* d_in, const int* in_sizes, int n_in,
                              void* d_out, int out_size, void* d_ws, size_t ws_size,
                              hipStream_t stream) {
    const float* const* in = (const float* const*)d_in;
    float* out = (float*)d_out;
    char* ws = (char*)d_ws;

    size_t off = 0;
    auto alloc = [&](size_t bytes) { size_t o = off; off += (bytes + 255) & ~(size_t)255; return o; };
    float*  A12   = (float*)(ws + alloc(12*N_*N_*4));
    float*  A12sq = (float*)(ws + alloc(12*N_*N_*4));
    __bf16* WcT   = (__bf16*)(ws + alloc((size_t)12*256*128*2));
    __bf16* WT    = (__bf16*)(ws + alloc((size_t)21*256*512*2));
    float*  accs  = (float*)(ws + alloc(256));
    __bf16* gout  = (__bf16*)(ws + alloc((size_t)12*ELEMS*2));
    __bf16* com   = (__bf16*)(ws + alloc((size_t)4*ELEMS*2));
    __bf16* hbf   = (__bf16*)(ws + alloc((size_t)7*ELEMS*2));
    __bf16* xAc   = (__bf16*)(ws + alloc((size_t)12*ROWS*128*2));

    XPtrs xp;
    for (int i = 0; i < 12; i++) xp.p[i] = in[i];
    HPtrs hp;
    for (int i = 0; i < 7; i++) hp.p[i] = in[15 + i];

    pre_kernel<<<10077, 256, 0, stream>>>(in[12], in[13], in[14], A12, A12sq,
                                          in[27], in[26], in[28], in[29],
                                          out + 7L*ELEMS + 4, accs,
                                          in[22], in[23], in[24], in[25], WcT,
                                          in[30], in[31], in[32], WT,
                                          hp, hbf);
    xa_kernel<<<dim3(12, 128), 256, 0, stream>>>(xp, A12, A12sq, xAc);

    // GCN: gout[r] = relu(xA1@W1) + relu(xA2@W2)
    {
        GB gb{};
        for (int z = 0; z < 12; z++) { gb.a0[z] = xAc + (long)z*ROWS*128; gb.a1[z] = gb.a0[z]; }
        gemm_bf16<4><<<dim3(2, 70, 12), 256, 0, stream>>>(
            gb, 128, 128, 128, 128,
            WcT, WcT, 256, 128, 32768L,
            gout, 256, ELEMS, (const __bf16*)nullptr, 0L);
    }

    // msh + sim + com
    {
        MshA ma{};
        ma.oa[0] = gout + 3L*ELEMS; ma.ob[0] = gout + 4L*ELEMS; ma.oc[0] = ma.oa[0];
        ma.oa[1] = gout + 5L*ELEMS; ma.ob[1] = gout + 6L*ELEMS; ma.oc[1] = ma.oa[1];
        ma.oa[2] = gout + 7L*ELEMS; ma.ob[2] = gout + 8L*ELEMS; ma.oc[2] = ma.oa[2];
        ma.oa[3] = gout + 9L*ELEMS; ma.ob[3] = gout + 10L*ELEMS; ma.oc[3] = gout + 11L*ELEMS;
        ma.S[0] = in[26]; ma.S[1] = in[27]; ma.S[2] = in[28]; ma.S[3] = in[29];
        ma.com = com; ma.accs = accs;
        msh_kernel<<<dim3(256, 4, 4), 256, 0, stream>>>(ma);
    }

    fin_kernel<<<1, 64, 0, stream>>>(accs, out + 7L*ELEMS);

    // Fused GRU v6s: single launch, XCD-chunked swizzle (B L2-resident per XCD)
    {
        GB gb{};
        for (int g = 0; g < 7; g++) {
            gb.a0[g] = (g < 3) ? gout + (long)g*ELEMS : com + (long)(g - 3)*ELEMS;
            gb.a1[g] = hbf + (long)g*ELEMS;
            gb.hp[g] = in[15 + g];
        }
        gru_fused<<<dim3(980), 512, 0, stream>>>(gb, WT, out);
    }
}